// Round 3
// baseline (2301.566 us; speedup 1.0000x reference)
//
#include <hip/hip_runtime.h>
#include <cstdint>
#include <cstddef>

#define N_NODES 50000
#define N_EDGES 800000
#define NB      256
#define IN_DIM  1024
#define HDIM    256   // HDIM/4 = 64 float4 per row

typedef __attribute__((ext_vector_type(8))) short bf16x8;
typedef __attribute__((ext_vector_type(4))) short s4v;
typedef __attribute__((ext_vector_type(4))) float f32x4;

__device__ __forceinline__ float sigmoidf_(float v) { return 1.0f / (1.0f + expf(-v)); }

// fp32 -> bf16 (RNE) bit tricks
__device__ __forceinline__ short f2bf(float f) {
    unsigned u = __float_as_uint(f);
    unsigned r = (u + 0x7FFFu + ((u >> 16) & 1u)) >> 16;
    return (short)r;
}
__device__ __forceinline__ float bf2f(short s) {
    return __uint_as_float(((unsigned)(unsigned short)s) << 16);
}

// ---------------- CSC build ----------------
__global__ void k_hist(const int* __restrict__ col, int* __restrict__ cnt, int n) {
    int e = blockIdx.x * 256 + threadIdx.x;
    if (e < n) atomicAdd(&cnt[col[e]], 1);
}

__global__ void k_scan1(const int* __restrict__ cnt, int* __restrict__ ptr,
                        int* __restrict__ bsums, int n) {
    __shared__ int sh[256];
    int t = threadIdx.x;
    int base = blockIdx.x * 2048 + t * 8;
    int v[8]; int s = 0;
#pragma unroll
    for (int i = 0; i < 8; ++i) { int idx = base + i; v[i] = (idx < n) ? cnt[idx] : 0; s += v[i]; }
    sh[t] = s;
    __syncthreads();
    for (int off = 1; off < 256; off <<= 1) {
        int x = (t >= off) ? sh[t - off] : 0;
        __syncthreads();
        sh[t] += x;
        __syncthreads();
    }
    int excl = sh[t] - s;
    if (t == 255) bsums[blockIdx.x] = sh[255];
    int run = excl;
#pragma unroll
    for (int i = 0; i < 8; ++i) { int idx = base + i; if (idx < n) ptr[idx] = run; run += v[i]; }
}

__global__ void k_scan2(int* __restrict__ bsums, int nb, int* __restrict__ ptr_n) {
    if (threadIdx.x == 0 && blockIdx.x == 0) {
        int run = 0;
        for (int i = 0; i < nb; ++i) { int v = bsums[i]; bsums[i] = run; run += v; }
        ptr_n[0] = run;
    }
}

__global__ void k_scan3(int* __restrict__ ptr, const int* __restrict__ bsums, int n) {
    int base = blockIdx.x * 2048 + threadIdx.x * 8;
    int add = bsums[blockIdx.x];
#pragma unroll
    for (int i = 0; i < 8; ++i) { int idx = base + i; if (idx < n) ptr[idx] += add; }
}

__global__ void k_copy_int(const int* __restrict__ a, int* __restrict__ b, int n) {
    int i = blockIdx.x * 256 + threadIdx.x;
    if (i < n) b[i] = a[i];
}

__global__ void k_scatter(const int* __restrict__ row, const int* __restrict__ col,
                          int* __restrict__ fill, int* __restrict__ src,
                          int* __restrict__ eid, int n) {
    int e = blockIdx.x * 256 + threadIdx.x;
    if (e < n) {
        int c = col[e];
        int p = atomicAdd(&fill[c], 1);
        src[p] = row[e];
        eid[p] = e;
    }
}

__global__ void k_dis1(const int* __restrict__ ptr, float* __restrict__ dis, int n) {
    int i = blockIdx.x * 256 + threadIdx.x;
    if (i < n) {
        float deg = 1.0f + (float)(ptr[i + 1] - ptr[i]);
        dis[i] = 1.0f / sqrtf(deg);
    }
}

// ---------------- weight prep: W[K][Nc=256] fp32 -> Bt_hi/Bt_lo [Nc][K] bf16 ----------------
__global__ void k_splitB(const float* __restrict__ W, short* __restrict__ bt_hi,
                         short* __restrict__ bt_lo, int K) {
    int idx = blockIdx.x * 256 + threadIdx.x;   // over Nc * K/4
    if (idx >= 256 * (K >> 2)) return;
    int n = idx & 255, kq = (idx >> 8) << 2;
    s4v h, l;
#pragma unroll
    for (int j = 0; j < 4; ++j) {
        float v = W[(size_t)(kq + j) * 256 + n];
        short hh = f2bf(v);
        h[j] = hh;
        l[j] = f2bf(v - bf2f(hh));
    }
    *reinterpret_cast<s4v*>(&bt_hi[(size_t)n * K + kq]) = h;
    *reinterpret_cast<s4v*>(&bt_lo[(size_t)n * K + kq]) = l;
}

// ---------------- split-bf16 MFMA GEMM: C[M,256] = A[M,K] @ B[K,256] ----------------
// AMODE: 0 = A fp32 (convert+split during staging); 1 = A pre-split bf16 pair (pure copy)
// OUT:   0 = fp32; 1 = split bf16 pair (hi/lo)
// 3 MFMA passes (hi*hi + hi*lo + lo*hi) into one fp32 acc (~fp32 accuracy).
// BM=128, BN=128, BK=32; 4 waves, each 64x64 (4x4 frags of 16x16x32).
// LDS rows padded to 40 bf16 (80B = 20 banks mod 32 -> only 2-way conflicts, free [m136]).
template <int AMODE, int OUT, int BIAS>
__global__ __launch_bounds__(256, 2) void k_gemm(const float* __restrict__ A32,
                                                 const short* __restrict__ AHg,
                                                 const short* __restrict__ ALg,
                                                 const short* __restrict__ BtHi,
                                                 const short* __restrict__ BtLo,
                                                 const float* __restrict__ bias,
                                                 float* __restrict__ C32,
                                                 short* __restrict__ CHg,
                                                 short* __restrict__ CLg,
                                                 int M, int K) {
    constexpr int LDT = 40;
    __shared__ short Ah[128 * LDT];
    __shared__ short Al[128 * LDT];
    __shared__ short Bh[128 * LDT];
    __shared__ short Bl[128 * LDT];

    int tid = threadIdx.x;
    int lane = tid & 63;
    int wave = tid >> 6;
    int wr = wave >> 1, wc = wave & 1;       // wave tile (64x64) coords
    int lr = lane & 15, kg = lane >> 4;      // fragment lane decomposition
    int m0 = blockIdx.y * 128, n0 = blockIdx.x * 128;

    f32x4 acc[4][4] = {};

    for (int k0 = 0; k0 < K; k0 += 32) {
        if constexpr (AMODE == 0) {
            // stage A tile: 128 x 32 fp32 -> hi/lo bf16 (conversion in-staging)
#pragma unroll
            for (int i = 0; i < 4; ++i) {
                int u = tid + i * 256;           // [0,1024): 128 rows x 8 float4-chunks
                int rowi = u >> 3, kq = (u & 7) << 2;
                int gr = m0 + rowi;
                float4 av = make_float4(0.f, 0.f, 0.f, 0.f);
                if (gr < M) av = *reinterpret_cast<const float4*>(A32 + (size_t)gr * K + (k0 + kq));
                short hx = f2bf(av.x), hy = f2bf(av.y), hz = f2bf(av.z), hw = f2bf(av.w);
                s4v h = {hx, hy, hz, hw};
                s4v l = {f2bf(av.x - bf2f(hx)), f2bf(av.y - bf2f(hy)),
                         f2bf(av.z - bf2f(hz)), f2bf(av.w - bf2f(hw))};
                *reinterpret_cast<s4v*>(&Ah[rowi * LDT + kq]) = h;
                *reinterpret_cast<s4v*>(&Al[rowi * LDT + kq]) = l;
            }
        } else {
            // stage A tile: pure 16B copies of pre-split bf16 pair
#pragma unroll
            for (int i = 0; i < 2; ++i) {
                int u = tid + i * 256;           // [0,512): 128 rows x 4 16B-chunks
                int rowi = u >> 2, kc = (u & 3) << 3;
                int gr = m0 + rowi;
                int4 h = make_int4(0, 0, 0, 0), l = make_int4(0, 0, 0, 0);
                if (gr < M) {
                    size_t g = (size_t)gr * K + k0 + kc;
                    h = *reinterpret_cast<const int4*>(AHg + g);
                    l = *reinterpret_cast<const int4*>(ALg + g);
                }
                *reinterpret_cast<int4*>(&Ah[rowi * LDT + kc]) = h;
                *reinterpret_cast<int4*>(&Al[rowi * LDT + kc]) = l;
            }
        }
        // stage B tile (128 n-rows x 32 k bf16, k-contiguous)
#pragma unroll
        for (int i = 0; i < 2; ++i) {
            int u = tid + i * 256;               // [0,512)
            int rowi = u >> 2, cq = (u & 3) << 3;
            const size_t g = (size_t)(n0 + rowi) * K + k0 + cq;
            int4 bh = *reinterpret_cast<const int4*>(BtHi + g);
            int4 bl = *reinterpret_cast<const int4*>(BtLo + g);
            *reinterpret_cast<int4*>(&Bh[rowi * LDT + cq]) = bh;
            *reinterpret_cast<int4*>(&Bl[rowi * LDT + cq]) = bl;
        }
        __syncthreads();

        bf16x8 a_h[4], a_l[4], b_h[4], b_l[4];
#pragma unroll
        for (int i = 0; i < 4; ++i) {
            int ar = wr * 64 + i * 16 + lr;
            a_h[i] = *reinterpret_cast<const bf16x8*>(&Ah[ar * LDT + kg * 8]);
            a_l[i] = *reinterpret_cast<const bf16x8*>(&Al[ar * LDT + kg * 8]);
            int br = wc * 64 + i * 16 + lr;
            b_h[i] = *reinterpret_cast<const bf16x8*>(&Bh[br * LDT + kg * 8]);
            b_l[i] = *reinterpret_cast<const bf16x8*>(&Bl[br * LDT + kg * 8]);
        }
#pragma unroll
        for (int i = 0; i < 4; ++i)
#pragma unroll
            for (int j = 0; j < 4; ++j) {
                acc[i][j] = __builtin_amdgcn_mfma_f32_16x16x32_bf16(a_h[i], b_h[j], acc[i][j], 0, 0, 0);
                acc[i][j] = __builtin_amdgcn_mfma_f32_16x16x32_bf16(a_h[i], b_l[j], acc[i][j], 0, 0, 0);
                acc[i][j] = __builtin_amdgcn_mfma_f32_16x16x32_bf16(a_l[i], b_h[j], acc[i][j], 0, 0, 0);
            }
        __syncthreads();
    }

    // epilogue: C/D layout col=lane&15, row=(lane>>4)*4+reg [m89]
#pragma unroll
    for (int i = 0; i < 4; ++i) {
#pragma unroll
        for (int j = 0; j < 4; ++j) {
#pragma unroll
            for (int r = 0; r < 4; ++r) {
                int gr = m0 + wr * 64 + i * 16 + kg * 4 + r;
                if (gr >= M) continue;
                int gc = n0 + wc * 64 + j * 16 + lr;
                float v = acc[i][j][r];
                if (BIAS) v += bias[gc];
                if constexpr (OUT == 0) {
                    C32[(size_t)gr * 256 + gc] = v;
                } else {
                    short h = f2bf(v);
                    CHg[(size_t)gr * 256 + gc] = h;
                    CLg[(size_t)gr * 256 + gc] = f2bf(v - bf2f(h));
                }
            }
        }
    }
}

// ---------------- GCN conv gather ----------------
// out = relu(dis_i*(sum_e w_e*xw[src] + dis_i*xw[i]) + bias); gather source fp32.
// MODE: 0 = edge weight 1, 1 = ew[eid], 2 = 1-ew[eid].  OUT: 0 = fp32, 1 = split bf16 pair.
template <int MODE, int OUT>
__global__ __launch_bounds__(256) void k_conv(const float* __restrict__ xw,
                                              const float* __restrict__ dis,
                                              const float* __restrict__ ew,
                                              const int* __restrict__ ptr,
                                              const int* __restrict__ srcA,
                                              const int* __restrict__ eidA,
                                              const float* __restrict__ bias,
                                              float* __restrict__ out32,
                                              short* __restrict__ outH,
                                              short* __restrict__ outL) {
    int node = blockIdx.x * 4 + (threadIdx.x >> 6);
    if (node >= N_NODES) return;
    int lane = threadIdx.x & 63;
    const float4* xw4 = reinterpret_cast<const float4*>(xw);
    int s = ptr[node], e = ptr[node + 1];
    float4 acc = make_float4(0.f, 0.f, 0.f, 0.f);
    int k = s;
    for (; k + 2 <= e; k += 2) {            // 2 independent row-gathers in flight
        int sr0 = srcA[k], sr1 = srcA[k + 1];
        float w0 = dis[sr0], w1 = dis[sr1];
        if (MODE == 1) { w0 *= ew[eidA[k]]; w1 *= ew[eidA[k + 1]]; }
        else if (MODE == 2) { w0 *= (1.0f - ew[eidA[k]]); w1 *= (1.0f - ew[eidA[k + 1]]); }
        float4 v0 = xw4[(size_t)sr0 * 64 + lane];
        float4 v1 = xw4[(size_t)sr1 * 64 + lane];
        acc.x = fmaf(w1, v1.x, fmaf(w0, v0.x, acc.x));
        acc.y = fmaf(w1, v1.y, fmaf(w0, v0.y, acc.y));
        acc.z = fmaf(w1, v1.z, fmaf(w0, v0.z, acc.z));
        acc.w = fmaf(w1, v1.w, fmaf(w0, v0.w, acc.w));
    }
    if (k < e) {
        int sr = srcA[k];
        float w = dis[sr];
        if (MODE == 1) w *= ew[eidA[k]];
        else if (MODE == 2) w *= (1.0f - ew[eidA[k]]);
        float4 v = xw4[(size_t)sr * 64 + lane];
        acc.x = fmaf(w, v.x, acc.x);
        acc.y = fmaf(w, v.y, acc.y);
        acc.z = fmaf(w, v.z, acc.z);
        acc.w = fmaf(w, v.w, acc.w);
    }
    float di = dis[node];
    float4 xv = xw4[(size_t)node * 64 + lane];
    float4 bv = reinterpret_cast<const float4*>(bias)[lane];
    float ox = fmaxf(fmaf(di, acc.x + di * xv.x, bv.x), 0.0f);
    float oy = fmaxf(fmaf(di, acc.y + di * xv.y, bv.y), 0.0f);
    float oz = fmaxf(fmaf(di, acc.z + di * xv.z, bv.z), 0.0f);
    float ow = fmaxf(fmaf(di, acc.w + di * xv.w, bv.w), 0.0f);
    size_t o4 = (size_t)node * 64 + lane;
    if constexpr (OUT == 0) {
        reinterpret_cast<float4*>(out32)[o4] = make_float4(ox, oy, oz, ow);
    } else {
        short hx = f2bf(ox), hy = f2bf(oy), hz = f2bf(oz), hw = f2bf(ow);
        s4v h = {hx, hy, hz, hw};
        s4v l = {f2bf(ox - bf2f(hx)), f2bf(oy - bf2f(hy)),
                 f2bf(oz - bf2f(hz)), f2bf(ow - bf2f(hw))};
        reinterpret_cast<s4v*>(outH)[o4] = h;
        reinterpret_cast<s4v*>(outL)[o4] = l;
    }
}

// ---------------- masker heads: node score + edge-score matvecs ----------------
__global__ __launch_bounds__(256) void k_nodescore(const float* __restrict__ h,
                                                   const float* __restrict__ node_w,
                                                   const float* __restrict__ node_b,
                                                   const float* __restrict__ edge_w,
                                                   float* __restrict__ ns,
                                                   float* __restrict__ en1,
                                                   float* __restrict__ en2) {
    int node = blockIdx.x * 4 + (threadIdx.x >> 6);
    if (node >= N_NODES) return;
    int lane = threadIdx.x & 63;
    float4 hv = reinterpret_cast<const float4*>(h)[(size_t)node * 64 + lane];
    float4 w1 = reinterpret_cast<const float4*>(node_w)[lane];
    float4 w2 = reinterpret_cast<const float4*>(edge_w)[lane];
    float4 w3 = reinterpret_cast<const float4*>(edge_w)[64 + lane];
    float d1 = hv.x * w1.x + hv.y * w1.y + hv.z * w1.z + hv.w * w1.w;
    float d2 = hv.x * w2.x + hv.y * w2.y + hv.z * w2.z + hv.w * w2.w;
    float d3 = hv.x * w3.x + hv.y * w3.y + hv.z * w3.z + hv.w * w3.w;
#pragma unroll
    for (int off = 32; off > 0; off >>= 1) {
        d1 += __shfl_xor(d1, off);
        d2 += __shfl_xor(d2, off);
        d3 += __shfl_xor(d3, off);
    }
    if (lane == 0) {
        ns[node] = sigmoidf_(d1 + node_b[0]);
        en1[node] = d2;
        en2[node] = d3;
    }
}

__global__ void k_edgescore(const int* __restrict__ row, const int* __restrict__ col,
                            const float* __restrict__ en1, const float* __restrict__ en2,
                            const float* __restrict__ eb, float* __restrict__ esc, int n) {
    int e = blockIdx.x * 256 + threadIdx.x;
    if (e < n) esc[e] = sigmoidf_(en1[row[e]] + en2[col[e]] + eb[0]);
}

__global__ void k_degcb(const int* __restrict__ ptr, const int* __restrict__ eidA,
                        const float* __restrict__ esc, float* __restrict__ dis_c,
                        float* __restrict__ dis_b, int n) {
    int i = blockIdx.x * 256 + threadIdx.x;
    if (i >= n) return;
    int s = ptr[i], e = ptr[i + 1];
    float t = 0.f;
    for (int k = s; k < e; ++k) t += esc[eidA[k]];
    float indeg = (float)(e - s);
    dis_c[i] = 1.0f / sqrtf(1.0f + t);
    dis_b[i] = 1.0f / sqrtf(1.0f + (indeg - t));
}

// ---------------- node-mask scale + bias -> split bf16 pair ----------------
template <bool INV>
__global__ void k_scale(const float* __restrict__ A, const float* __restrict__ ns,
                        const float* __restrict__ bias,
                        short* __restrict__ oh, short* __restrict__ ol) {
    int idx = blockIdx.x * 256 + threadIdx.x;  // over N*64 float4s
    int node = idx >> 6, q = idx & 63;
    float s = ns[node];
    if (INV) s = 1.0f - s;
    float4 v = reinterpret_cast<const float4*>(A)[idx];
    float4 b = reinterpret_cast<const float4*>(bias)[q];
    float rx = fmaf(s, v.x, b.x), ry = fmaf(s, v.y, b.y);
    float rz = fmaf(s, v.z, b.z), rw = fmaf(s, v.w, b.w);
    short hx = f2bf(rx), hy = f2bf(ry), hz = f2bf(rz), hw = f2bf(rw);
    s4v h = {hx, hy, hz, hw};
    s4v l = {f2bf(rx - bf2f(hx)), f2bf(ry - bf2f(hy)),
             f2bf(rz - bf2f(hz)), f2bf(rw - bf2f(hw))};
    reinterpret_cast<s4v*>(oh)[idx] = h;
    reinterpret_cast<s4v*>(ol)[idx] = l;
}

// ---------------- pooling ----------------
__global__ void k_starts(const int* __restrict__ batch, int* __restrict__ starts) {
    int b = threadIdx.x;
    if (b > NB) return;
    int lo = 0, hi = N_NODES;
    while (lo < hi) { int mid = (lo + hi) >> 1; if (batch[mid] < b) lo = mid + 1; else hi = mid; }
    starts[b] = lo;
}

__global__ __launch_bounds__(256) void k_pool(const float* __restrict__ h,
                                              const int* __restrict__ starts,
                                              float* __restrict__ out) {
    int b = blockIdx.x, ch = threadIdx.x;
    int s = starts[b], e = starts[b + 1];
    float acc = 0.f;
    for (int i = s; i < e; ++i) acc += h[(size_t)i * HDIM + ch];
    out[b * HDIM + ch] = acc / fmaxf((float)(e - s), 1.0f);
}

// ---------------- classifier heads + per-graph loss ----------------
__global__ __launch_bounds__(64) void k_head(const float* __restrict__ score_c,
                                             const float* __restrict__ score_b,
                                             const int* __restrict__ y,
                                             const int* __restrict__ perm,
                                             const float* __restrict__ wc,
                                             const float* __restrict__ bc,
                                             const float* __restrict__ wb,
                                             const float* __restrict__ bb,
                                             float* __restrict__ pred_out,
                                             float* __restrict__ loss_part) {
    int b = blockIdx.x, lane = threadIdx.x;
    int pidx = perm[b];
    float4 vc = reinterpret_cast<const float4*>(score_c)[b * 64 + lane];
    float4 vb = reinterpret_cast<const float4*>(score_b)[b * 64 + lane];
    float4 vp = reinterpret_cast<const float4*>(score_b)[pidx * 64 + lane];
    const float4* wc4 = reinterpret_cast<const float4*>(wc);
    const float4* wb4 = reinterpret_cast<const float4*>(wb);
    float4 cA0 = wc4[lane * 2], cA1 = wc4[lane * 2 + 1];
    float4 cB0 = wc4[128 + lane * 2], cB1 = wc4[128 + lane * 2 + 1];
    float4 bA0 = wb4[lane * 2], bA1 = wb4[lane * 2 + 1];
    float4 bB0 = wb4[128 + lane * 2], bB1 = wb4[128 + lane * 2 + 1];

    float c1_0 = vc.x * cA0.x + vc.y * cA0.z + vc.z * cA1.x + vc.w * cA1.z;
    float c1_1 = vc.x * cA0.y + vc.y * cA0.w + vc.z * cA1.y + vc.w * cA1.w;
    float c2_0 = vb.x * cB0.x + vb.y * cB0.z + vb.z * cB1.x + vb.w * cB1.z;
    float c2_1 = vb.x * cB0.y + vb.y * cB0.w + vb.z * cB1.y + vb.w * cB1.w;
    float cp_0 = vp.x * cB0.x + vp.y * cB0.z + vp.z * cB1.x + vp.w * cB1.z;
    float cp_1 = vp.x * cB0.y + vp.y * cB0.w + vp.z * cB1.y + vp.w * cB1.w;
    float b1_0 = vc.x * bA0.x + vc.y * bA0.z + vc.z * bA1.x + vc.w * bA1.z;
    float b1_1 = vc.x * bA0.y + vc.y * bA0.w + vc.z * bA1.y + vc.w * bA1.w;
    float b2_0 = vb.x * bB0.x + vb.y * bB0.z + vb.z * bB1.x + vb.w * bB1.z;
    float b2_1 = vb.x * bB0.y + vb.y * bB0.w + vb.z * bB1.y + vb.w * bB1.w;
    float bp_0 = vp.x * bB0.x + vp.y * bB0.z + vp.z * bB1.x + vp.w * bB1.z;
    float bp_1 = vp.x * bB0.y + vp.y * bB0.w + vp.z * bB1.y + vp.w * bB1.w;

#pragma unroll
    for (int off = 32; off > 0; off >>= 1) {
        c1_0 += __shfl_xor(c1_0, off); c1_1 += __shfl_xor(c1_1, off);
        c2_0 += __shfl_xor(c2_0, off); c2_1 += __shfl_xor(c2_1, off);
        cp_0 += __shfl_xor(cp_0, off); cp_1 += __shfl_xor(cp_1, off);
        b1_0 += __shfl_xor(b1_0, off); b1_1 += __shfl_xor(b1_1, off);
        b2_0 += __shfl_xor(b2_0, off); b2_1 += __shfl_xor(b2_1, off);
        bp_0 += __shfl_xor(bp_0, off); bp_1 += __shfl_xor(bp_1, off);
    }
    if (lane == 0) {
        float pc0 = c1_0 + c2_0 + bc[0], pc1 = c1_1 + c2_1 + bc[1];
        float pb0 = b1_0 + b2_0 + bb[0], pb1 = b1_1 + b2_1 + bb[1];
        float pmc0 = c1_0 + cp_0 + bc[0], pmc1 = c1_1 + cp_1 + bc[1];
        float pma0 = b1_0 + bp_0 + bb[0], pma1 = b1_1 + bp_1 + bb[1];
        int yy = y[b], yp = y[pidx];

        float m1 = fmaxf(pc0, pc1);
        float lse1 = m1 + logf(expf(pc0 - m1) + expf(pc1 - m1));
        float ce_c = lse1 - (yy == 0 ? pc0 : pc1);
        float m2 = fmaxf(pb0, pb1);
        float lse2 = m2 + logf(expf(pb0 - m2) + expf(pb1 - m2));
        float ly2 = (yy == 0 ? pb0 : pb1);
        float gce_b = (lse2 - ly2) * powf(expf(ly2 - lse2), 0.7f) * 0.7f;
        float m3 = fmaxf(pmc0, pmc1);
        float lse3 = m3 + logf(expf(pmc0 - m3) + expf(pmc1 - m3));
        float ce_mc = lse3 - (yy == 0 ? pmc0 : pmc1);
        float m4 = fmaxf(pma0, pma1);
        float lse4 = m4 + logf(expf(pma0 - m4) + expf(pma1 - m4));
        float ly4 = (yp == 0 ? pma0 : pma1);
        float gce_ma = (lse4 - ly4) * powf(expf(ly4 - lse4), 0.7f) * 0.7f;

        loss_part[b] = (ce_c + gce_b + 15.0f * (ce_mc + gce_ma)) * (1.0f / (float)NB);
        pred_out[b * 2 + 0] = pc0;
        pred_out[b * 2 + 1] = pc1;
    }
}

__global__ void k_lossred(const float* __restrict__ part, float* __restrict__ out) {
    __shared__ float sh[256];
    int t = threadIdx.x;
    sh[t] = part[t];
    __syncthreads();
    for (int off = 128; off > 0; off >>= 1) {
        if (t < off) sh[t] += sh[t + off];
        __syncthreads();
    }
    if (t == 0) out[0] = sh[0];
}

// ---------------- orchestration ----------------
extern "C" void kernel_launch(void* const* d_in, const int* in_sizes, int n_in,
                              void* d_out, int out_size, void* d_ws, size_t ws_size,
                              hipStream_t stream) {
    (void)in_sizes; (void)n_in; (void)out_size; (void)ws_size;
    const float* x      = (const float*)d_in[0];
    const int*   ei     = (const int*)d_in[1];
    const int*   batch  = (const int*)d_in[2];
    const int*   y      = (const int*)d_in[3];
    const int*   perm   = (const int*)d_in[4];
    const float* m_fc_w = (const float*)d_in[5],  *m_fc_b = (const float*)d_in[6];
    const float* m_c1_w = (const float*)d_in[7],  *m_c1_b = (const float*)d_in[8];
    const float* m_c2_w = (const float*)d_in[9],  *m_c2_b = (const float*)d_in[10];
    const float* m_nd_w = (const float*)d_in[11], *m_nd_b = (const float*)d_in[12];
    const float* m_ed_w = (const float*)d_in[13], *m_ed_b = (const float*)d_in[14];
    const float* c_fc_w = (const float*)d_in[15], *c_fc_b = (const float*)d_in[16];
    const float* c_c1_w = (const float*)d_in[17], *c_c1_b = (const float*)d_in[18];
    const float* c_c2_w = (const float*)d_in[19], *c_c2_b = (const float*)d_in[20];
    const float* b_fc_w = (const float*)d_in[21], *b_fc_b = (const float*)d_in[22];
    const float* b_c1_w = (const float*)d_in[23], *b_c1_b = (const float*)d_in[24];
    const float* b_c2_w = (const float*)d_in[25], *b_c2_b = (const float*)d_in[26];
    const float* mlp_c_w = (const float*)d_in[27], *mlp_c_b = (const float*)d_in[28];
    const float* mlp_b_w = (const float*)d_in[29], *mlp_b_b = (const float*)d_in[30];
    const int* row = ei;
    const int* col = ei + N_EDGES;

    char* p = (char*)d_ws;
    auto alloc = [&](size_t bytes) -> void* {
        uintptr_t q = ((uintptr_t)p + 255) & ~(uintptr_t)255;
        p = (char*)(q + bytes);
        return (void*)q;
    };
    // fp32 activation buffers (aliased across pipeline stages)
    float* F1 = (float*)alloc((size_t)N_NODES * HDIM * 4);
    float* F2 = (float*)alloc((size_t)N_NODES * HDIM * 4);
    // split bf16 activation pairs
    short* S1h = (short*)alloc((size_t)N_NODES * HDIM * 2);
    short* S1l = (short*)alloc((size_t)N_NODES * HDIM * 2);
    short* S2h = (short*)alloc((size_t)N_NODES * HDIM * 2);
    short* S2l = (short*)alloc((size_t)N_NODES * HDIM * 2);
    int* cnt    = (int*)alloc((size_t)N_NODES * 4);          // also reused as fill
    int* ptr    = (int*)alloc((size_t)(N_NODES + 1) * 4);
    int* bsums  = (int*)alloc(32 * 4);
    int* csrc   = (int*)alloc((size_t)N_EDGES * 4);
    int* ceid   = (int*)alloc((size_t)N_EDGES * 4);
    float* dis1 = (float*)alloc((size_t)N_NODES * 4);
    float* dis_c = (float*)alloc((size_t)N_NODES * 4);
    float* dis_b = (float*)alloc((size_t)N_NODES * 4);
    float* ns   = (float*)alloc((size_t)N_NODES * 4);
    float* en1  = (float*)alloc((size_t)N_NODES * 4);
    float* en2  = (float*)alloc((size_t)N_NODES * 4);
    float* esc  = (float*)alloc((size_t)N_EDGES * 4);
    float* sc   = (float*)alloc((size_t)NB * HDIM * 4);
    float* sb   = (float*)alloc((size_t)NB * HDIM * 4);
    int* starts = (int*)alloc((size_t)(NB + 1) * 4);
    float* lpart = (float*)alloc((size_t)NB * 4);
    // pre-split transposed weights (bf16 hi/lo), [256][K] each
    short* wsp[9][2];
    const int wk[9] = {IN_DIM, HDIM, HDIM, IN_DIM, HDIM, HDIM, IN_DIM, HDIM, HDIM};
    for (int i = 0; i < 9; ++i) {
        wsp[i][0] = (short*)alloc((size_t)256 * wk[i] * 2);
        wsp[i][1] = (short*)alloc((size_t)256 * wk[i] * 2);
    }
    const float* wsrc[9] = {m_fc_w, m_c1_w, m_c2_w, c_fc_w, c_c1_w, c_c2_w,
                            b_fc_w, b_c1_w, b_c2_w};

    const int EB = N_EDGES / 256;          // 3125
    const int NBk = (N_NODES + 255) / 256; // 196
    const int NW = N_NODES / 4;            // 12500 (wave-per-node kernels)
    const dim3 gG(2, (N_NODES + 127) / 128);  // 2 x 391 GEMM grid

    // ---- CSC build + weight prep ----
    hipMemsetAsync(cnt, 0, (size_t)N_NODES * 4, stream);
    k_hist<<<EB, 256, 0, stream>>>(col, cnt, N_EDGES);
    k_scan1<<<25, 256, 0, stream>>>(cnt, ptr, bsums, N_NODES);
    k_scan2<<<1, 64, 0, stream>>>(bsums, 25, ptr + N_NODES);
    k_scan3<<<25, 256, 0, stream>>>(ptr, bsums, N_NODES);
    k_copy_int<<<NBk, 256, 0, stream>>>(ptr, cnt, N_NODES);
    k_scatter<<<EB, 256, 0, stream>>>(row, col, cnt, csrc, ceid, N_EDGES);
    k_dis1<<<NBk, 256, 0, stream>>>(ptr, dis1, N_NODES);
    k_starts<<<1, 512, 0, stream>>>(batch, starts);
    for (int i = 0; i < 9; ++i)
        k_splitB<<<(256 * (wk[i] >> 2) + 255) / 256, 256, 0, stream>>>(
            wsrc[i], wsp[i][0], wsp[i][1], wk[i]);

    // ---- masker ----
    k_gemm<0, 1, 1><<<gG, 256, 0, stream>>>(x, nullptr, nullptr, wsp[0][0], wsp[0][1],
                                            m_fc_b, nullptr, S1h, S1l, N_NODES, IN_DIM);
    k_gemm<1, 0, 0><<<gG, 256, 0, stream>>>(nullptr, S1h, S1l, wsp[1][0], wsp[1][1],
                                            nullptr, F1, nullptr, nullptr, N_NODES, HDIM);
    k_conv<0, 1><<<NW, 256, 0, stream>>>(F1, dis1, nullptr, ptr, csrc, ceid, m_c1_b,
                                         nullptr, S2h, S2l);
    k_gemm<1, 0, 0><<<gG, 256, 0, stream>>>(nullptr, S2h, S2l, wsp[2][0], wsp[2][1],
                                            nullptr, F2, nullptr, nullptr, N_NODES, HDIM);
    k_conv<0, 0><<<NW, 256, 0, stream>>>(F2, dis1, nullptr, ptr, csrc, ceid, m_c2_b,
                                         F1, nullptr, nullptr);
    k_nodescore<<<NW, 256, 0, stream>>>(F1, m_nd_w, m_nd_b, m_ed_w, ns, en1, en2);
    k_edgescore<<<EB, 256, 0, stream>>>(row, col, en1, en2, m_ed_b, esc, N_EDGES);
    k_degcb<<<NBk, 256, 0, stream>>>(ptr, ceid, esc, dis_c, dis_b, N_NODES);

    // ---- c-net ----
    k_gemm<0, 0, 0><<<gG, 256, 0, stream>>>(x, nullptr, nullptr, wsp[3][0], wsp[3][1],
                                            nullptr, F2, nullptr, nullptr, N_NODES, IN_DIM);
    k_scale<false><<<NW, 256, 0, stream>>>(F2, ns, c_fc_b, S1h, S1l);
    k_gemm<1, 0, 0><<<gG, 256, 0, stream>>>(nullptr, S1h, S1l, wsp[4][0], wsp[4][1],
                                            nullptr, F2, nullptr, nullptr, N_NODES, HDIM);
    k_conv<1, 1><<<NW, 256, 0, stream>>>(F2, dis_c, esc, ptr, csrc, ceid, c_c1_b,
                                         nullptr, S2h, S2l);
    k_gemm<1, 0, 0><<<gG, 256, 0, stream>>>(nullptr, S2h, S2l, wsp[5][0], wsp[5][1],
                                            nullptr, F2, nullptr, nullptr, N_NODES, HDIM);
    k_conv<1, 0><<<NW, 256, 0, stream>>>(F2, dis_c, esc, ptr, csrc, ceid, c_c2_b,
                                         F1, nullptr, nullptr);
    k_pool<<<NB, 256, 0, stream>>>(F1, starts, sc);

    // ---- b-net ----
    k_gemm<0, 0, 0><<<gG, 256, 0, stream>>>(x, nullptr, nullptr, wsp[6][0], wsp[6][1],
                                            nullptr, F2, nullptr, nullptr, N_NODES, IN_DIM);
    k_scale<true><<<NW, 256, 0, stream>>>(F2, ns, b_fc_b, S1h, S1l);
    k_gemm<1, 0, 0><<<gG, 256, 0, stream>>>(nullptr, S1h, S1l, wsp[7][0], wsp[7][1],
                                            nullptr, F2, nullptr, nullptr, N_NODES, HDIM);
    k_conv<2, 1><<<NW, 256, 0, stream>>>(F2, dis_b, esc, ptr, csrc, ceid, b_c1_b,
                                         nullptr, S2h, S2l);
    k_gemm<1, 0, 0><<<gG, 256, 0, stream>>>(nullptr, S2h, S2l, wsp[8][0], wsp[8][1],
                                            nullptr, F2, nullptr, nullptr, N_NODES, HDIM);
    k_conv<2, 0><<<NW, 256, 0, stream>>>(F2, dis_b, esc, ptr, csrc, ceid, b_c2_b,
                                         F1, nullptr, nullptr);
    k_pool<<<NB, 256, 0, stream>>>(F1, starts, sb);

    // ---- heads + loss ----
    float* outp = (float*)d_out;
    k_head<<<NB, 64, 0, stream>>>(sc, sb, y, perm, mlp_c_w, mlp_c_b, mlp_b_w, mlp_b_b,
                                  outp, lpart);
    k_lossred<<<1, 256, 0, stream>>>(lpart, outp + NB * 2);
}